// Round 6
// baseline (874.298 us; speedup 1.0000x reference)
//
#include <hip/hip_runtime.h>

#define N_NODES 100000
#define N_EDGES 1600000
#define IN_F 128
#define OUT_F 64

#define BROWS 32               // rows per bucket (100000 = 32 * 3125)
#define NBUCKET 3125
#define NHBLK 64               // histogram/reorder blocks (bigger runs -> coalesced reorder writes)
#define EPB (N_EDGES / NHBLK)  // 25000 edges per hist block
#define ASTRIDE 65             // LDS acc row stride (spreads ds_add banks)

__device__ __forceinline__ unsigned short f32_to_bf16(float f) {
    const unsigned int b = __float_as_uint(f);
    return (unsigned short)((b + 0x7FFFu + ((b >> 16) & 1u)) >> 16);   // RNE
}

// ---------------- Kernel 1: support(bf16) = X @ W (fp32 vector ALU) ----------------
__global__ __launch_bounds__(256) void gemm_kernel(
    const float* __restrict__ x, const float* __restrict__ w,
    unsigned short* __restrict__ support) {
    __shared__ float4 w4_lds[IN_F * 16];     // 32 KB
    __shared__ float4 x4_lds[64 * 33];       // 33.8 KB (pad kills 4-way conflict)

    const int t = threadIdx.x;
    const int rowbase = blockIdx.x * 64;
    {
        const float4* w4 = (const float4*)w;
        #pragma unroll
        for (int i = 0; i < 8; ++i) w4_lds[t + 256 * i] = w4[t + 256 * i];
    }
    {
        const float4* xg = (const float4*)x;
        #pragma unroll
        for (int i = 0; i < 8; ++i) {
            const int f4i = t + 256 * i;
            const int r = f4i >> 5, kk = f4i & 31;
            const int gr = min(rowbase + r, N_NODES - 1);
            x4_lds[r * 33 + kk] = xg[(size_t)gr * 32 + kk];
        }
    }
    __syncthreads();

    const int cg = t & 15;
    const int rg = t >> 4;
    float4 acc[4];
    #pragma unroll
    for (int j = 0; j < 4; ++j) acc[j] = make_float4(0.f, 0.f, 0.f, 0.f);

    #pragma unroll 4
    for (int k4 = 0; k4 < 32; ++k4) {
        float4 wv[4], xv[4];
        #pragma unroll
        for (int q = 0; q < 4; ++q) wv[q] = w4_lds[(k4 * 4 + q) * 16 + cg];
        #pragma unroll
        for (int j = 0; j < 4; ++j) xv[j] = x4_lds[(rg * 4 + j) * 33 + k4];
        #pragma unroll
        for (int j = 0; j < 4; ++j) {
            acc[j].x += xv[j].x * wv[0].x + xv[j].y * wv[1].x + xv[j].z * wv[2].x + xv[j].w * wv[3].x;
            acc[j].y += xv[j].x * wv[0].y + xv[j].y * wv[1].y + xv[j].z * wv[2].y + xv[j].w * wv[3].y;
            acc[j].z += xv[j].x * wv[0].z + xv[j].y * wv[1].z + xv[j].z * wv[2].z + xv[j].w * wv[3].z;
            acc[j].w += xv[j].x * wv[0].w + xv[j].y * wv[1].w + xv[j].z * wv[2].w + xv[j].w * wv[3].w;
        }
    }

    #pragma unroll
    for (int j = 0; j < 4; ++j) {
        const int r = rowbase + rg * 4 + j;
        if (r < N_NODES) {
            ushort4 s;
            s.x = f32_to_bf16(acc[j].x); s.y = f32_to_bf16(acc[j].y);
            s.z = f32_to_bf16(acc[j].z); s.w = f32_to_bf16(acc[j].w);
            *(ushort4*)&support[(size_t)r * OUT_F + cg * 4] = s;
        }
    }
}

// ---------------- Kernel 2: per-block LDS histogram of dst buckets ----------------
__global__ __launch_bounds__(256) void hist_kernel(const int* __restrict__ erow,
                                                   int* __restrict__ C) {
    __shared__ int h[NBUCKET];   // 12.5 KB
    for (int i = threadIdx.x; i < NBUCKET; i += 256) h[i] = 0;
    __syncthreads();
    const int e0 = blockIdx.x * EPB;
    for (int i = threadIdx.x; i < EPB; i += 256)
        atomicAdd(&h[erow[e0 + i] >> 5], 1);
    __syncthreads();
    for (int i = threadIdx.x; i < NBUCKET; i += 256)
        C[i * NHBLK + blockIdx.x] = h[i];
}

// ---------------- Kernel 3: exclusive scan of each bucket's 64 block-counts ----------------
__global__ void scan_kernel(int* __restrict__ C, int* __restrict__ base) {
    const int k = blockIdx.x;        // bucket
    const int lane = threadIdx.x;    // 64 threads = 1 wave
    const int v = C[k * NHBLK + lane];
    int incl = v;
    #pragma unroll
    for (int d = 1; d < 64; d <<= 1) { int tv = __shfl_up(incl, d); if (lane >= d) incl += tv; }
    C[k * NHBLK + lane] = incl - v;
    if (lane == 63) base[k] = incl;
}

// ---------------- Kernel 4: exclusive scan of bucket totals (one wave) ----------------
#define BPL ((NBUCKET + 63) / 64)   // 49 per lane
__global__ void base_kernel(int* __restrict__ base) {
    const int lane = threadIdx.x;
    int v[BPL]; int s = 0;
    #pragma unroll
    for (int j = 0; j < BPL; ++j) { const int i = lane * BPL + j; v[j] = (i < NBUCKET) ? base[i] : 0; s += v[j]; }
    int incl = s;
    #pragma unroll
    for (int d = 1; d < 64; d <<= 1) { int tv = __shfl_up(incl, d); if (lane >= d) incl += tv; }
    int run = incl - s;
    #pragma unroll
    for (int j = 0; j < BPL; ++j) { const int i = lane * BPL + j; if (i < NBUCKET) base[i] = run; run += v[j]; }
    if (lane == 63) base[NBUCKET] = incl;
}

// ---------------- Kernel 5: reorder edges into bucket-contiguous arrays ----------------
// rec packs src (bits 0..19) and dst-within-bucket (bits 20..24).
__global__ __launch_bounds__(256) void reorder_kernel(
    const int* __restrict__ erow, const int* __restrict__ ecol,
    const float* __restrict__ evals, const int* __restrict__ C,
    const int* __restrict__ base, int* __restrict__ srec, float* __restrict__ sval) {
    __shared__ int loff[NBUCKET];   // 12.5 KB
    for (int i = threadIdx.x; i < NBUCKET; i += 256)
        loff[i] = base[i] + C[i * NHBLK + blockIdx.x];
    __syncthreads();
    const int e0 = blockIdx.x * EPB;
    for (int i = threadIdx.x; i < EPB; i += 256) {
        const int e = e0 + i;
        const int dst = erow[e];
        const int p = atomicAdd(&loff[dst >> 5], 1);   // LDS atomic
        srec[p] = ecol[e] | ((dst & 31) << 20);
        sval[p] = evals[e];
    }
}

// ---------------- Kernel 6: multi-edge dwordx4 gather + LDS accumulate + bias ----------------
// Lane layout: edge-in-group = lane>>3, feature-octet = lane&7. One dwordx4 load
// covers 8 edges x 16B (8 bf16). Four loads' results (rg[0..3]) must coexist ->
// compiler is forced to keep 16 result VGPRs in flight (the R5 MLP failure fix).
__global__ __launch_bounds__(256) void gather_kernel(
    const unsigned short* __restrict__ support, const int* __restrict__ srec,
    const float* __restrict__ sval, const int* __restrict__ base,
    const float* __restrict__ bias, float* __restrict__ out) {
    __shared__ float acc[BROWS * ASTRIDE];   // 8.32 KB
    const int t = threadIdx.x;
    for (int i = t; i < BROWS * ASTRIDE; i += 256) acc[i] = 0.f;
    __syncthreads();

    const int k = blockIdx.x;
    const int wid = t >> 6;
    const int lane = t & 63;
    const int g8 = lane >> 3;   // edge within group-of-8
    const int f8 = lane & 7;    // feature octet
    const int start = base[k], end = base[k + 1];

    // 32 edges per wave-iteration (4 load-groups of 8), 128 per block-round.
    for (int e0 = start + wid * 32; e0 < end; e0 += 128) {
        int rec[4]; float val[4];
        #pragma unroll
        for (int b = 0; b < 4; ++b) {
            const int e = e0 + b * 8 + g8;
            const int ec = min(e, end - 1);           // loop guard => end > start
            rec[b] = srec[ec];
            val[b] = (e < end) ? sval[ec] : 0.f;      // masked tail contributes 0
        }
        uint4 rg[4];
        #pragma unroll
        for (int b = 0; b < 4; ++b)
            rg[b] = *(const uint4*)&support[(size_t)(rec[b] & 0xFFFFF) * OUT_F + f8 * 8];
        #pragma unroll
        for (int b = 0; b < 4; ++b) {
            const float v = val[b];
            float* a = &acc[(rec[b] >> 20) * ASTRIDE + f8 * 8];
            unsigned int u;
            u = rg[b].x;
            atomicAdd(a + 0, __uint_as_float(u << 16) * v);
            atomicAdd(a + 1, __uint_as_float(u & 0xFFFF0000u) * v);
            u = rg[b].y;
            atomicAdd(a + 2, __uint_as_float(u << 16) * v);
            atomicAdd(a + 3, __uint_as_float(u & 0xFFFF0000u) * v);
            u = rg[b].z;
            atomicAdd(a + 4, __uint_as_float(u << 16) * v);
            atomicAdd(a + 5, __uint_as_float(u & 0xFFFF0000u) * v);
            u = rg[b].w;
            atomicAdd(a + 6, __uint_as_float(u << 16) * v);
            atomicAdd(a + 7, __uint_as_float(u & 0xFFFF0000u) * v);
        }
    }
    __syncthreads();

    const int row0 = k * BROWS;
    const float bb = bias[t & 63];   // column is invariant under i += 256
    for (int i = t; i < BROWS * OUT_F; i += 256) {
        const int r = i >> 6, c = i & 63;
        out[(size_t)(row0 + r) * OUT_F + c] = acc[r * ASTRIDE + c] + bb;
    }
}

// ---------------- Fallback (ws too small): bias-init + atomic scatter (bf16 support) ----------------
__global__ __launch_bounds__(256) void init_out_kernel(const float* __restrict__ bias,
                                                       float* __restrict__ out) {
    const size_t i = (size_t)blockIdx.x * 256 + threadIdx.x;
    if (i < (size_t)N_NODES * OUT_F) out[i] = bias[i & 63];
}
__global__ __launch_bounds__(256) void scatter_atomic_kernel(
    const unsigned short* __restrict__ support, const int* __restrict__ erow,
    const int* __restrict__ ecol, const float* __restrict__ evals,
    float* __restrict__ out) {
    const int wid = (blockIdx.x * 256 + threadIdx.x) >> 6;
    const int nw = gridDim.x * 4;
    const int lane = threadIdx.x & 63;
    const int n_iters = N_EDGES / 8;
    for (int it0 = wid; it0 < n_iters; it0 += nw) {
        const int e0 = __builtin_amdgcn_readfirstlane(it0) * 8;
        int src[8], dst[8]; float val[8];
        #pragma unroll
        for (int u = 0; u < 8; ++u) { src[u] = ecol[e0 + u]; dst[u] = erow[e0 + u]; val[u] = evals[e0 + u]; }
        float g[8];
        #pragma unroll
        for (int u = 0; u < 8; ++u) {
            const unsigned int us = support[(size_t)src[u] * OUT_F + lane];
            g[u] = __uint_as_float(us << 16);
        }
        #pragma unroll
        for (int u = 0; u < 8; ++u) atomicAdd(&out[(size_t)dst[u] * OUT_F + lane], g[u] * val[u]);
    }
}

extern "C" void kernel_launch(void* const* d_in, const int* in_sizes, int n_in,
                              void* d_out, int out_size, void* d_ws, size_t ws_size,
                              hipStream_t stream) {
    const float* x     = (const float*)d_in[0];
    const float* w     = (const float*)d_in[1];
    const float* bias  = (const float*)d_in[2];
    const int* erow    = (const int*)d_in[3];
    const int* ecol    = (const int*)d_in[4];
    const float* evals = (const float*)d_in[5];
    float* out = (float*)d_out;

    char* p = (char*)d_ws;
    unsigned short* support = (unsigned short*)p;     size_t o = (size_t)N_NODES * OUT_F * 2;  // 12.8 MB
    int* C    = (int*)(p + o);                        o += (size_t)NBUCKET * NHBLK * 4;        // 800 KB
    int* base = (int*)(p + o);                        o += ((NBUCKET + 1) * 4 + 255) / 256 * 256;
    int* srec = (int*)(p + o);                        o += (size_t)N_EDGES * 4;                // 6.4 MB
    float* sval = (float*)(p + o);                    o += (size_t)N_EDGES * 4;                // 6.4 MB

    gemm_kernel<<<(N_NODES + 63) / 64, 256, 0, stream>>>(x, w, support);

    if (ws_size >= o) {
        hist_kernel<<<NHBLK, 256, 0, stream>>>(erow, C);
        scan_kernel<<<NBUCKET, 64, 0, stream>>>(C, base);
        base_kernel<<<1, 64, 0, stream>>>(base);
        reorder_kernel<<<NHBLK, 256, 0, stream>>>(erow, ecol, evals, C, base, srec, sval);
        gather_kernel<<<NBUCKET, 256, 0, stream>>>(support, srec, sval, base, bias, out);
    } else {
        init_out_kernel<<<((N_NODES * OUT_F) + 255) / 256, 256, 0, stream>>>(bias, out);
        scatter_atomic_kernel<<<2048, 256, 0, stream>>>(support, erow, ecol, evals, out);
    }
}

// Round 7
// 332.560 us; speedup vs baseline: 2.6290x; 2.6290x over previous
//
#include <hip/hip_runtime.h>

#define N_NODES 100000
#define N_EDGES 1600000
#define IN_F 128
#define OUT_F 64

#define BROWS 32               // rows per bucket (100000 = 32 * 3125)
#define NBUCKET 3125
#define NHBLK 64               // histogram/reorder blocks; runs of ~8 edges * 8B = 64B lines
#define EPB (N_EDGES / NHBLK)  // 25000 edges per hist block
#define CAP 1024               // max edges a gather block sorts (Poisson(512): P(>1024)~0)

__device__ __forceinline__ unsigned short f32_to_bf16(float f) {
    const unsigned int b = __float_as_uint(f);
    return (unsigned short)((b + 0x7FFFu + ((b >> 16) & 1u)) >> 16);   // RNE
}
__device__ __forceinline__ float bf16_to_f32(unsigned short u) {
    return __uint_as_float(((unsigned int)u) << 16);
}

// ---------------- Kernel 1: support(bf16) = X @ W (fp32 vector ALU) ----------------
__global__ __launch_bounds__(256) void gemm_kernel(
    const float* __restrict__ x, const float* __restrict__ w,
    unsigned short* __restrict__ support) {
    __shared__ float4 w4_lds[IN_F * 16];     // 32 KB
    __shared__ float4 x4_lds[64 * 33];       // 33.8 KB (pad kills 4-way conflict)

    const int t = threadIdx.x;
    const int rowbase = blockIdx.x * 64;
    {
        const float4* w4 = (const float4*)w;
        #pragma unroll
        for (int i = 0; i < 8; ++i) w4_lds[t + 256 * i] = w4[t + 256 * i];
    }
    {
        const float4* xg = (const float4*)x;
        #pragma unroll
        for (int i = 0; i < 8; ++i) {
            const int f4i = t + 256 * i;
            const int r = f4i >> 5, kk = f4i & 31;
            const int gr = min(rowbase + r, N_NODES - 1);
            x4_lds[r * 33 + kk] = xg[(size_t)gr * 32 + kk];
        }
    }
    __syncthreads();

    const int cg = t & 15;
    const int rg = t >> 4;
    float4 acc[4];
    #pragma unroll
    for (int j = 0; j < 4; ++j) acc[j] = make_float4(0.f, 0.f, 0.f, 0.f);

    // unroll 2 (was 4): 4*unroll float4 operands in flight; unroll 4 likely spilled.
    #pragma unroll 2
    for (int k4 = 0; k4 < 32; ++k4) {
        float4 wv[4], xv[4];
        #pragma unroll
        for (int q = 0; q < 4; ++q) wv[q] = w4_lds[(k4 * 4 + q) * 16 + cg];
        #pragma unroll
        for (int j = 0; j < 4; ++j) xv[j] = x4_lds[(rg * 4 + j) * 33 + k4];
        #pragma unroll
        for (int j = 0; j < 4; ++j) {
            acc[j].x += xv[j].x * wv[0].x + xv[j].y * wv[1].x + xv[j].z * wv[2].x + xv[j].w * wv[3].x;
            acc[j].y += xv[j].x * wv[0].y + xv[j].y * wv[1].y + xv[j].z * wv[2].y + xv[j].w * wv[3].y;
            acc[j].z += xv[j].x * wv[0].z + xv[j].y * wv[1].z + xv[j].z * wv[2].z + xv[j].w * wv[3].z;
            acc[j].w += xv[j].x * wv[0].w + xv[j].y * wv[1].w + xv[j].z * wv[2].w + xv[j].w * wv[3].w;
        }
    }

    #pragma unroll
    for (int j = 0; j < 4; ++j) {
        const int r = rowbase + rg * 4 + j;
        if (r < N_NODES) {
            ushort4 s;
            s.x = f32_to_bf16(acc[j].x); s.y = f32_to_bf16(acc[j].y);
            s.z = f32_to_bf16(acc[j].z); s.w = f32_to_bf16(acc[j].w);
            *(ushort4*)&support[(size_t)r * OUT_F + cg * 4] = s;
        }
    }
}

// ---------------- Kernel 2: per-block LDS histogram of dst buckets ----------------
__global__ __launch_bounds__(256) void hist_kernel(const int* __restrict__ erow,
                                                   int* __restrict__ C) {
    __shared__ int h[NBUCKET];   // 12.5 KB
    for (int i = threadIdx.x; i < NBUCKET; i += 256) h[i] = 0;
    __syncthreads();
    const int e0 = blockIdx.x * EPB;
    for (int i = threadIdx.x; i < EPB; i += 256)
        atomicAdd(&h[erow[e0 + i] >> 5], 1);
    __syncthreads();
    for (int i = threadIdx.x; i < NBUCKET; i += 256)
        C[i * NHBLK + blockIdx.x] = h[i];
}

// ---------------- Kernel 3: exclusive scan of each bucket's 64 block-counts ----------------
__global__ void scan_kernel(int* __restrict__ C, int* __restrict__ base) {
    const int k = blockIdx.x;        // bucket
    const int lane = threadIdx.x;    // 64 threads = 1 wave
    const int v = C[k * NHBLK + lane];
    int incl = v;
    #pragma unroll
    for (int d = 1; d < 64; d <<= 1) { int tv = __shfl_up(incl, d); if (lane >= d) incl += tv; }
    C[k * NHBLK + lane] = incl - v;
    if (lane == 63) base[k] = incl;
}

// ---------------- Kernel 4: exclusive scan of bucket totals (one wave) ----------------
#define BPL ((NBUCKET + 63) / 64)   // 49 per lane
__global__ void base_kernel(int* __restrict__ base) {
    const int lane = threadIdx.x;
    int v[BPL]; int s = 0;
    #pragma unroll
    for (int j = 0; j < BPL; ++j) { const int i = lane * BPL + j; v[j] = (i < NBUCKET) ? base[i] : 0; s += v[j]; }
    int incl = s;
    #pragma unroll
    for (int d = 1; d < 64; d <<= 1) { int tv = __shfl_up(incl, d); if (lane >= d) incl += tv; }
    int run = incl - s;
    #pragma unroll
    for (int j = 0; j < BPL; ++j) { const int i = lane * BPL + j; if (i < NBUCKET) base[i] = run; run += v[j]; }
    if (lane == 63) base[NBUCKET] = incl;
}

// ---------------- Kernel 5: reorder edges into bucket-contiguous uint2 array ----------------
// sedge[p] = { src | (dst&31)<<20 , bits(val) }  — one 8B payload => 64B-line runs.
__global__ __launch_bounds__(256) void reorder_kernel(
    const int* __restrict__ erow, const int* __restrict__ ecol,
    const float* __restrict__ evals, const int* __restrict__ C,
    const int* __restrict__ base, uint2* __restrict__ sedge) {
    __shared__ int loff[NBUCKET];   // 12.5 KB
    for (int i = threadIdx.x; i < NBUCKET; i += 256)
        loff[i] = base[i] + C[i * NHBLK + blockIdx.x];
    __syncthreads();
    const int e0 = blockIdx.x * EPB;
    for (int i = threadIdx.x; i < EPB; i += 256) {
        const int e = e0 + i;
        const int dst = erow[e];
        const int p = atomicAdd(&loff[dst >> 5], 1);   // LDS atomic
        uint2 ed;
        ed.x = (unsigned int)ecol[e] | (((unsigned int)dst & 31u) << 20);
        ed.y = __float_as_uint(evals[e]);
        sedge[p] = ed;
    }
}

// ---------------- Kernel 6: counting-sort by row + register accumulation ----------------
// No ds_add_f32, no global atomics. Per block: sort its bucket's edges by dst row
// in LDS, then wave w register-accumulates rows 8w..8w+7 (lane = feature, bf16
// gathers in batches of 8 for MLP), one plain store per row.
__global__ __launch_bounds__(256) void gather_kernel(
    const unsigned short* __restrict__ support, const uint2* __restrict__ sedge,
    const int* __restrict__ base, const float* __restrict__ bias,
    float* __restrict__ out) {
    __shared__ uint2 sdata[CAP];    // 8 KB sorted payloads
    __shared__ int bcnt[BROWS];
    __shared__ int bptr[BROWS + 1];
    __shared__ int boff[BROWS];

    const int t = threadIdx.x;
    const int k = blockIdx.x;
    const int start = base[k], end = base[k + 1];
    const int n = min(end - start, CAP);

    if (t < BROWS) bcnt[t] = 0;
    __syncthreads();

    // load + bin-count (<=4 edges/thread; ~1 LDS-atomic lane-op per edge)
    uint2 my[4]; int mb[4];
    #pragma unroll
    for (int j = 0; j < 4; ++j) {
        const int i = t + j * 256;
        mb[j] = -1;
        if (i < n) {
            my[j] = sedge[start + i];
            mb[j] = (my[j].x >> 20) & 31;
            atomicAdd(&bcnt[mb[j]], 1);
        }
    }
    __syncthreads();

    // exclusive scan of 32 bins (first wave)
    if (t < 64) {
        const int lane = t;
        const int v = (lane < BROWS) ? bcnt[lane] : 0;
        int incl = v;
        #pragma unroll
        for (int d = 1; d < 32; d <<= 1) { int tv = __shfl_up(incl, d); if (lane >= d) incl += tv; }
        if (lane < BROWS) { bptr[lane] = incl - v; boff[lane] = incl - v; }
        if (lane == BROWS - 1) bptr[BROWS] = incl;
    }
    __syncthreads();

    // scatter payloads into row-sorted order
    #pragma unroll
    for (int j = 0; j < 4; ++j) {
        if (mb[j] >= 0) {
            const int p = atomicAdd(&boff[mb[j]], 1);
            sdata[p] = my[j];
        }
    }
    __syncthreads();

    // register accumulation: wave wid handles rows wid*8 .. wid*8+7
    const int wid = t >> 6, lane = t & 63;
    const float bb = bias[lane];
    for (int r8 = 0; r8 < 8; ++r8) {
        const int r = wid * 8 + r8;
        const int s0 = bptr[r], s1 = bptr[r + 1];
        float acc = 0.f;
        int j = s0;
        for (; j + 8 <= s1; j += 8) {
            uint2 ed[8];
            #pragma unroll
            for (int u = 0; u < 8; ++u) ed[u] = sdata[j + u];   // broadcast ds_read_b64
            float g[8];
            #pragma unroll
            for (int u = 0; u < 8; ++u)                          // 8 gathers in flight
                g[u] = bf16_to_f32(support[(size_t)(ed[u].x & 0xFFFFFu) * OUT_F + lane]);
            #pragma unroll
            for (int u = 0; u < 8; ++u)
                acc += g[u] * __uint_as_float(ed[u].y);
        }
        for (; j < s1; ++j) {
            const uint2 ed = sdata[j];
            acc += bf16_to_f32(support[(size_t)(ed.x & 0xFFFFFu) * OUT_F + lane])
                   * __uint_as_float(ed.y);
        }
        out[(size_t)(k * BROWS + r) * OUT_F + lane] = acc + bb;
    }

    // overflow insurance (never triggers for this distribution)
    if (end - start > CAP) {
        __syncthreads();
        for (int i = CAP + wid; i < end - start; i += 4) {
            const uint2 ed = sedge[start + i];
            const float g = bf16_to_f32(support[(size_t)(ed.x & 0xFFFFFu) * OUT_F + lane]);
            atomicAdd(&out[(size_t)(k * BROWS + ((ed.x >> 20) & 31)) * OUT_F + lane],
                      g * __uint_as_float(ed.y));
        }
    }
}

// ---------------- Fallback (ws too small): bias-init + atomic scatter (bf16 support) ----------------
__global__ __launch_bounds__(256) void init_out_kernel(const float* __restrict__ bias,
                                                       float* __restrict__ out) {
    const size_t i = (size_t)blockIdx.x * 256 + threadIdx.x;
    if (i < (size_t)N_NODES * OUT_F) out[i] = bias[i & 63];
}
__global__ __launch_bounds__(256) void scatter_atomic_kernel(
    const unsigned short* __restrict__ support, const int* __restrict__ erow,
    const int* __restrict__ ecol, const float* __restrict__ evals,
    float* __restrict__ out) {
    const int wid = (blockIdx.x * 256 + threadIdx.x) >> 6;
    const int nw = gridDim.x * 4;
    const int lane = threadIdx.x & 63;
    const int n_iters = N_EDGES / 8;
    for (int it0 = wid; it0 < n_iters; it0 += nw) {
        const int e0 = __builtin_amdgcn_readfirstlane(it0) * 8;
        int src[8], dst[8]; float val[8];
        #pragma unroll
        for (int u = 0; u < 8; ++u) { src[u] = ecol[e0 + u]; dst[u] = erow[e0 + u]; val[u] = evals[e0 + u]; }
        float g[8];
        #pragma unroll
        for (int u = 0; u < 8; ++u) g[u] = bf16_to_f32(support[(size_t)src[u] * OUT_F + lane]);
        #pragma unroll
        for (int u = 0; u < 8; ++u) atomicAdd(&out[(size_t)dst[u] * OUT_F + lane], g[u] * val[u]);
    }
}

extern "C" void kernel_launch(void* const* d_in, const int* in_sizes, int n_in,
                              void* d_out, int out_size, void* d_ws, size_t ws_size,
                              hipStream_t stream) {
    const float* x     = (const float*)d_in[0];
    const float* w     = (const float*)d_in[1];
    const float* bias  = (const float*)d_in[2];
    const int* erow    = (const int*)d_in[3];
    const int* ecol    = (const int*)d_in[4];
    const float* evals = (const float*)d_in[5];
    float* out = (float*)d_out;

    char* p = (char*)d_ws;
    unsigned short* support = (unsigned short*)p;     size_t o = (size_t)N_NODES * OUT_F * 2;  // 12.8 MB
    int* C    = (int*)(p + o);                        o += (size_t)NBUCKET * NHBLK * 4;        // 800 KB
    int* base = (int*)(p + o);                        o += ((NBUCKET + 1) * 4 + 255) / 256 * 256;
    uint2* sedge = (uint2*)(p + o);                   o += (size_t)N_EDGES * 8;                // 12.8 MB

    gemm_kernel<<<(N_NODES + 63) / 64, 256, 0, stream>>>(x, w, support);

    if (ws_size >= o) {
        hist_kernel<<<NHBLK, 256, 0, stream>>>(erow, C);
        scan_kernel<<<NBUCKET, 64, 0, stream>>>(C, base);
        base_kernel<<<1, 64, 0, stream>>>(base);
        reorder_kernel<<<NHBLK, 256, 0, stream>>>(erow, ecol, evals, C, base, sedge);
        gather_kernel<<<NBUCKET, 256, 0, stream>>>(support, sedge, base, bias, out);
    } else {
        init_out_kernel<<<((N_NODES * OUT_F) + 255) / 256, 256, 0, stream>>>(bias, out);
        scatter_atomic_kernel<<<2048, 256, 0, stream>>>(support, erow, ecol, evals, out);
    }
}

// Round 8
// 319.614 us; speedup vs baseline: 2.7355x; 1.0405x over previous
//
#include <hip/hip_runtime.h>

#define N_NODES 100000
#define N_EDGES 1600000
#define IN_F 128
#define OUT_F 64

#define BROWS 32               // rows per bucket (100000 = 32 * 3125)
#define NBUCKET 3125
#define CAP 1024               // max edges a gather block sorts (mean 512, std 22.6)
#define BK_PAD 136             // padded k-stride (shorts) for b_lds: breaks 16-way bank repeat

typedef __attribute__((ext_vector_type(8))) short bf16x8;
typedef __attribute__((ext_vector_type(4))) float f32x4;

__device__ __forceinline__ unsigned short f32_to_bf16(float f) {
    const unsigned int b = __float_as_uint(f);
    return (unsigned short)((b + 0x7FFFu + ((b >> 16) & 1u)) >> 16);   // RNE
}
__device__ __forceinline__ float bf16_to_f32(unsigned short u) {
    return __uint_as_float(((unsigned int)u) << 16);
}

// ---------------- Kernel 1: support(bf16) = X @ W via MFMA 16x16x32 bf16 ----------------
// Block = 256 thr = 4 waves; wave handles 16 rows x 64 cols. W transposed in LDS
// as [n][k] bf16 (pad 136) so b-frags are ds_read_b128. A-frags read straight from
// global x (each element once, 32B/lane chunks). Frag layouts (m89/m91-verified):
// A: m=lane&15, k=quad*8+j.  B: n=lane&15, k=quad*8+j.  C/D: col=lane&15, row=quad*4+r.
__global__ __launch_bounds__(256) void gemm_kernel(
    const float* __restrict__ x, const float* __restrict__ w,
    unsigned short* __restrict__ support) {
    __shared__ unsigned short b_lds[OUT_F * BK_PAD];   // 17.4 KB

    const int t = threadIdx.x;
    // stage W transposed: w[k][n] (fp32, coalesced float4) -> b_lds[n*BK_PAD + k] (bf16)
    #pragma unroll
    for (int i = 0; i < 8; ++i) {
        const int f = t + 256 * i;            // float4 index; k = f>>4, n4 = (f&15)*4
        const int k = f >> 4, n4 = (f & 15) * 4;
        const float4 wv = ((const float4*)w)[f];
        b_lds[(n4 + 0) * BK_PAD + k] = f32_to_bf16(wv.x);
        b_lds[(n4 + 1) * BK_PAD + k] = f32_to_bf16(wv.y);
        b_lds[(n4 + 2) * BK_PAD + k] = f32_to_bf16(wv.z);
        b_lds[(n4 + 3) * BK_PAD + k] = f32_to_bf16(wv.w);
    }
    __syncthreads();

    const int lane = t & 63, wid = t >> 6;
    const int m16 = lane & 15, quad = lane >> 4;
    const int row0 = blockIdx.x * 64 + wid * 16;
    const int arow = min(row0 + m16, N_NODES - 1);
    const float* xr = x + (size_t)arow * IN_F;

    f32x4 acc[4];
    #pragma unroll
    for (int nt = 0; nt < 4; ++nt) acc[nt] = (f32x4){0.f, 0.f, 0.f, 0.f};

    #pragma unroll
    for (int kt = 0; kt < 4; ++kt) {
        const int kb = kt * 32 + quad * 8;
        const float4 a0 = *(const float4*)(xr + kb);
        const float4 a1 = *(const float4*)(xr + kb + 4);
        bf16x8 af;
        af[0] = (short)f32_to_bf16(a0.x); af[1] = (short)f32_to_bf16(a0.y);
        af[2] = (short)f32_to_bf16(a0.z); af[3] = (short)f32_to_bf16(a0.w);
        af[4] = (short)f32_to_bf16(a1.x); af[5] = (short)f32_to_bf16(a1.y);
        af[6] = (short)f32_to_bf16(a1.z); af[7] = (short)f32_to_bf16(a1.w);
        #pragma unroll
        for (int nt = 0; nt < 4; ++nt) {
            const bf16x8 bf = *(const bf16x8*)&b_lds[(nt * 16 + m16) * BK_PAD + kb];
            acc[nt] = __builtin_amdgcn_mfma_f32_16x16x32_bf16(af, bf, acc[nt], 0, 0, 0);
        }
    }

    #pragma unroll
    for (int nt = 0; nt < 4; ++nt) {
        #pragma unroll
        for (int r = 0; r < 4; ++r) {
            const int row = row0 + quad * 4 + r;
            if (row < N_NODES)
                support[(size_t)row * OUT_F + nt * 16 + m16] = f32_to_bf16(acc[nt][r]);
        }
    }
}

// ---------------- Kernel 2a: zero bucket counters ----------------
__global__ void zero_kernel(int* __restrict__ gcount) {
    for (int i = threadIdx.x; i < NBUCKET; i += 256) gcount[i] = 0;
}

// ---------------- Kernel 2b: bucket histogram (LDS partial -> global atomic) ----------------
#define CBLK 256
#define CEPB (N_EDGES / CBLK)   // 6250
__global__ __launch_bounds__(256) void count_kernel(const int* __restrict__ erow,
                                                    int* __restrict__ gcount) {
    __shared__ int h[NBUCKET];   // 12.5 KB
    for (int i = threadIdx.x; i < NBUCKET; i += 256) h[i] = 0;
    __syncthreads();
    const int e0 = blockIdx.x * CEPB;
    for (int i = threadIdx.x; i < CEPB; i += 256)
        atomicAdd(&h[erow[e0 + i] >> 5], 1);
    __syncthreads();
    for (int i = threadIdx.x; i < NBUCKET; i += 256)
        if (h[i]) atomicAdd(&gcount[i], h[i]);
}

// ---------------- Kernel 3: exclusive scan of bucket totals -> base, cursor ----------------
#define BPL ((NBUCKET + 63) / 64)   // 49 per lane
__global__ void base_kernel(const int* __restrict__ gcount, int* __restrict__ base,
                            int* __restrict__ cursor) {
    const int lane = threadIdx.x;
    int v[BPL]; int s = 0;
    #pragma unroll
    for (int j = 0; j < BPL; ++j) { const int i = lane * BPL + j; v[j] = (i < NBUCKET) ? gcount[i] : 0; s += v[j]; }
    int incl = s;
    #pragma unroll
    for (int d = 1; d < 64; d <<= 1) { int tv = __shfl_up(incl, d); if (lane >= d) incl += tv; }
    int run = incl - s;
    #pragma unroll
    for (int j = 0; j < BPL; ++j) {
        const int i = lane * BPL + j;
        if (i < NBUCKET) { base[i] = run; cursor[i] = run; run += v[j]; }
    }
    if (lane == 63) base[NBUCKET] = incl;
}

// ---------------- Kernel 4: reorder via global atomic-ret slot allocation ----------------
// Fully parallel grid-stride (the R7 115us kernel was 64 blocks = 25% of CUs).
// ~512 RMWs per counter spread over 3125 L2 addresses; order within bucket is
// non-deterministic (sum is order-independent within fp tolerance).
__global__ __launch_bounds__(256) void reorder_kernel(
    const int* __restrict__ erow, const int* __restrict__ ecol,
    const float* __restrict__ evals, int* __restrict__ cursor,
    uint2* __restrict__ sedge) {
    const int stride = gridDim.x * 256;
    for (int e = blockIdx.x * 256 + threadIdx.x; e < N_EDGES; e += stride) {
        const int dst = erow[e];
        const int p = atomicAdd(&cursor[dst >> 5], 1);
        uint2 ed;
        ed.x = (unsigned int)ecol[e] | (((unsigned int)dst & 31u) << 20);
        ed.y = __float_as_uint(evals[e]);
        sedge[p] = ed;
    }
}

// ---------------- Kernel 5: counting-sort by row + register accumulation ----------------
__global__ __launch_bounds__(256) void gather_kernel(
    const unsigned short* __restrict__ support, const uint2* __restrict__ sedge,
    const int* __restrict__ base, const float* __restrict__ bias,
    float* __restrict__ out) {
    __shared__ uint2 sdata[CAP];    // 8 KB sorted payloads
    __shared__ int bcnt[BROWS];
    __shared__ int bptr[BROWS + 1];
    __shared__ int boff[BROWS];

    const int t = threadIdx.x;
    const int k = blockIdx.x;
    const int start = base[k], end = base[k + 1];
    const int n = min(end - start, CAP);

    if (t < BROWS) bcnt[t] = 0;
    __syncthreads();

    uint2 my[4]; int mb[4];
    #pragma unroll
    for (int j = 0; j < 4; ++j) {
        const int i = t + j * 256;
        mb[j] = -1;
        if (i < n) {
            my[j] = sedge[start + i];
            mb[j] = (my[j].x >> 20) & 31;
            atomicAdd(&bcnt[mb[j]], 1);
        }
    }
    __syncthreads();

    if (t < 64) {
        const int lane = t;
        const int v = (lane < BROWS) ? bcnt[lane] : 0;
        int incl = v;
        #pragma unroll
        for (int d = 1; d < 32; d <<= 1) { int tv = __shfl_up(incl, d); if (lane >= d) incl += tv; }
        if (lane < BROWS) { bptr[lane] = incl - v; boff[lane] = incl - v; }
        if (lane == BROWS - 1) bptr[BROWS] = incl;
    }
    __syncthreads();

    #pragma unroll
    for (int j = 0; j < 4; ++j) {
        if (mb[j] >= 0) {
            const int p = atomicAdd(&boff[mb[j]], 1);
            sdata[p] = my[j];
        }
    }
    __syncthreads();

    const int wid = t >> 6, lane = t & 63;
    const float bb = bias[lane];
    for (int r8 = 0; r8 < 8; ++r8) {
        const int r = wid * 8 + r8;
        const int s0 = bptr[r], s1 = bptr[r + 1];
        float acc = 0.f;
        int j = s0;
        for (; j + 8 <= s1; j += 8) {
            uint2 ed[8];
            #pragma unroll
            for (int u = 0; u < 8; ++u) ed[u] = sdata[j + u];
            float g[8];
            #pragma unroll
            for (int u = 0; u < 8; ++u)
                g[u] = bf16_to_f32(support[(size_t)(ed[u].x & 0xFFFFFu) * OUT_F + lane]);
            #pragma unroll
            for (int u = 0; u < 8; ++u)
                acc += g[u] * __uint_as_float(ed[u].y);
        }
        for (; j < s1; ++j) {
            const uint2 ed = sdata[j];
            acc += bf16_to_f32(support[(size_t)(ed.x & 0xFFFFFu) * OUT_F + lane])
                   * __uint_as_float(ed.y);
        }
        out[(size_t)(k * BROWS + r) * OUT_F + lane] = acc + bb;
    }

    if (end - start > CAP) {   // overflow insurance (statistically never)
        __syncthreads();
        for (int i = CAP + wid; i < end - start; i += 4) {
            const uint2 ed = sedge[start + i];
            const float g = bf16_to_f32(support[(size_t)(ed.x & 0xFFFFFu) * OUT_F + lane]);
            atomicAdd(&out[(size_t)(k * BROWS + ((ed.x >> 20) & 31)) * OUT_F + lane],
                      g * __uint_as_float(ed.y));
        }
    }
}

// ---------------- Fallback (ws too small): bias-init + atomic scatter ----------------
__global__ __launch_bounds__(256) void init_out_kernel(const float* __restrict__ bias,
                                                       float* __restrict__ out) {
    const size_t i = (size_t)blockIdx.x * 256 + threadIdx.x;
    if (i < (size_t)N_NODES * OUT_F) out[i] = bias[i & 63];
}
__global__ __launch_bounds__(256) void scatter_atomic_kernel(
    const unsigned short* __restrict__ support, const int* __restrict__ erow,
    const int* __restrict__ ecol, const float* __restrict__ evals,
    float* __restrict__ out) {
    const int wid = (blockIdx.x * 256 + threadIdx.x) >> 6;
    const int nw = gridDim.x * 4;
    const int lane = threadIdx.x & 63;
    const int n_iters = N_EDGES / 8;
    for (int it0 = wid; it0 < n_iters; it0 += nw) {
        const int e0 = __builtin_amdgcn_readfirstlane(it0) * 8;
        int src[8], dst[8]; float val[8];
        #pragma unroll
        for (int u = 0; u < 8; ++u) { src[u] = ecol[e0 + u]; dst[u] = erow[e0 + u]; val[u] = evals[e0 + u]; }
        float g[8];
        #pragma unroll
        for (int u = 0; u < 8; ++u) g[u] = bf16_to_f32(support[(size_t)src[u] * OUT_F + lane]);
        #pragma unroll
        for (int u = 0; u < 8; ++u) atomicAdd(&out[(size_t)dst[u] * OUT_F + lane], g[u] * val[u]);
    }
}

extern "C" void kernel_launch(void* const* d_in, const int* in_sizes, int n_in,
                              void* d_out, int out_size, void* d_ws, size_t ws_size,
                              hipStream_t stream) {
    const float* x     = (const float*)d_in[0];
    const float* w     = (const float*)d_in[1];
    const float* bias  = (const float*)d_in[2];
    const int* erow    = (const int*)d_in[3];
    const int* ecol    = (const int*)d_in[4];
    const float* evals = (const float*)d_in[5];
    float* out = (float*)d_out;

    char* p = (char*)d_ws;
    unsigned short* support = (unsigned short*)p;     size_t o = (size_t)N_NODES * OUT_F * 2;  // 12.8 MB
    int* gcount = (int*)(p + o);                      o += (NBUCKET + 3) / 4 * 16;
    int* base   = (int*)(p + o);                      o += (NBUCKET + 1 + 3) / 4 * 16;
    int* cursor = (int*)(p + o);                      o += (NBUCKET + 3) / 4 * 16;
    uint2* sedge = (uint2*)(p + o);                   o += (size_t)N_EDGES * 8;                // 12.8 MB

    gemm_kernel<<<(N_NODES + 63) / 64, 256, 0, stream>>>(x, w, support);

    if (ws_size >= o) {
        zero_kernel<<<1, 256, 0, stream>>>(gcount);
        count_kernel<<<CBLK, 256, 0, stream>>>(erow, gcount);
        base_kernel<<<1, 64, 0, stream>>>(gcount, base, cursor);
        reorder_kernel<<<1024, 256, 0, stream>>>(erow, ecol, evals, cursor, sedge);
        gather_kernel<<<NBUCKET, 256, 0, stream>>>(support, sedge, base, bias, out);
    } else {
        init_out_kernel<<<((N_NODES * OUT_F) + 255) / 256, 256, 0, stream>>>(bias, out);
        scatter_atomic_kernel<<<2048, 256, 0, stream>>>(support, erow, ecol, evals, out);
    }
}